// Round 1
// 1088.831 us; speedup vs baseline: 1.3770x; 1.3770x over previous
//
#include <hip/hip_runtime.h>

#define H 128

// ---------------------------------------------------------------------------
// Fold per-relation linears into W1:
//   A_r[m][j] = sum_i Wl[r][i][m] * W1[j][r*H+i]      (mat = r in 0..2)
//   B[m][j]   = sum_r sum_i Wr[r][i][m] * W1[j][r*H+i] (mat = 3)
//   cvec[j]   = b1[j] + sum_r sum_i bl[r][i] * W1[j][r*H+i]
//   W2T[m][j] = W2[j][m]
// ---------------------------------------------------------------------------
__global__ __launch_bounds__(128) void precompute_kernel(
    const float* __restrict__ Wl, const float* __restrict__ bl,
    const float* __restrict__ Wr, const float* __restrict__ W1,
    const float* __restrict__ b1, const float* __restrict__ W2,
    const float* __restrict__ b2,
    float* __restrict__ Am, float* __restrict__ W2T,
    float* __restrict__ cvec, float* __restrict__ b2f)
{
  int b = blockIdx.x;
  int j = threadIdx.x;
  if (b < 512) {
    int mat = b >> 7;      // 0..3
    int m   = b & 127;
    float s = 0.f;
    if (mat < 3) {
      int r = mat;
      for (int i = 0; i < H; i++)
        s += Wl[r*H*H + i*H + m] * W1[j*3*H + r*H + i];
    } else {
      for (int r = 0; r < 3; r++)
        for (int i = 0; i < H; i++)
          s += Wr[r*H*H + i*H + m] * W1[j*3*H + r*H + i];
    }
    Am[mat*H*H + m*H + j] = s;
  } else if (b == 512) {
    float s = b1[j];
    for (int r = 0; r < 3; r++)
      for (int i = 0; i < H; i++)
        s += bl[r*H + i] * W1[j*3*H + r*H + i];
    cvec[j] = s;
    b2f[j]  = b2[j];
  } else {
    int m = b - 513;       // 0..127
    W2T[m*H + j] = W2[j*H + m];
  }
}

// ---------------------------- CSR build (3 relations batched via gridDim.y) -
__global__ __launch_bounds__(256) void k_hist3(
    const int* __restrict__ ed0, const int* __restrict__ ed1,
    const int* __restrict__ ed2, int* __restrict__ cntA,
    int NU, int E0, int E1, int E2)
{
  int r = blockIdx.y;
  const int* ed = (r == 0) ? ed0 : (r == 1) ? ed1 : ed2;
  int E = (r == 0) ? E0 : (r == 1) ? E1 : E2;
  int i = blockIdx.x * 256 + threadIdx.x;
  if (i < E) atomicAdd(&cntA[(size_t)r * NU + ed[i]], 1);
}

__global__ __launch_bounds__(256) void k_scan1(
    const int* __restrict__ degA, int* __restrict__ offA,
    int* __restrict__ bsumA, int n, int nb1)
{
  int r = blockIdx.y;
  const int* deg = degA + (size_t)r * n;
  int* off1 = offA + (size_t)r * (n + 1);
  int* bsum = bsumA + (size_t)r * nb1;
  __shared__ int tmp[256];
  int i = blockIdx.x * 256 + threadIdx.x;
  int v = (i < n) ? deg[i] : 0;
  tmp[threadIdx.x] = v;
  __syncthreads();
  for (int s = 1; s < 256; s <<= 1) {
    int t = (threadIdx.x >= (unsigned)s) ? tmp[threadIdx.x - s] : 0;
    __syncthreads();
    tmp[threadIdx.x] += t;
    __syncthreads();
  }
  if (i < n) off1[i + 1] = tmp[threadIdx.x];     // local inclusive, block offset pending
  if (threadIdx.x == 255) bsum[blockIdx.x] = tmp[255];
}

__global__ __launch_bounds__(1024) void k_scan2(int* __restrict__ bsumA,
                                                int nb, int nb1)
{
  int* bsum = bsumA + (size_t)blockIdx.y * nb1;
  __shared__ int tmp[1024];
  __shared__ int carry;
  if (threadIdx.x == 0) carry = 0;
  __syncthreads();
  for (int base = 0; base < nb; base += 1024) {
    int i = base + threadIdx.x;
    int v = (i < nb) ? bsum[i] : 0;
    tmp[threadIdx.x] = v;
    __syncthreads();
    for (int s = 1; s < 1024; s <<= 1) {
      int t = (threadIdx.x >= (unsigned)s) ? tmp[threadIdx.x - s] : 0;
      __syncthreads();
      tmp[threadIdx.x] += t;
      __syncthreads();
    }
    if (i < nb) bsum[i] = carry + tmp[threadIdx.x] - v;   // exclusive
    __syncthreads();
    if (threadIdx.x == 0) carry += tmp[1023];
    __syncthreads();
  }
}

// scan3 + copy fused: off[i+1] finalized; cur[i] = off[i+1] - deg[i] = off[i]
__global__ __launch_bounds__(256) void k_scan3c(
    int* __restrict__ offA, const int* __restrict__ bsumA,
    int* __restrict__ curA, int n, int nb1)
{
  int r = blockIdx.y;
  int* off = offA + (size_t)r * (n + 1);
  const int* bsum = bsumA + (size_t)r * nb1;
  int* cur = curA + (size_t)r * n;
  int i = blockIdx.x * 256 + threadIdx.x;
  if (i < n) {
    int d = cur[i];                       // deg (hist result, about to be repurposed)
    int o = off[i + 1] + bsum[blockIdx.x];
    off[i + 1] = o;
    cur[i] = o - d;                       // start offset = cursor
  }
  if (blockIdx.x == 0 && threadIdx.x == 0) off[0] = 0;
}

__global__ __launch_bounds__(256) void k_scatter3(
    const int* __restrict__ es0, const int* __restrict__ es1,
    const int* __restrict__ es2,
    const int* __restrict__ ed0, const int* __restrict__ ed1,
    const int* __restrict__ ed2,
    int* __restrict__ curA,
    int* __restrict__ nbr0, int* __restrict__ nbr1, int* __restrict__ nbr2,
    int NU, int E0, int E1, int E2)
{
  int r = blockIdx.y;
  const int* es = (r == 0) ? es0 : (r == 1) ? es1 : es2;
  const int* ed = (r == 0) ? ed0 : (r == 1) ? ed1 : ed2;
  int* nbr = (r == 0) ? nbr0 : (r == 1) ? nbr1 : nbr2;
  int* cur = curA + (size_t)r * NU;
  int E = (r == 0) ? E0 : (r == 1) ? E1 : E2;
  int i = blockIdx.x * 256 + threadIdx.x;
  if (i < E) {
    int d = ed[i];
    int pos = atomicAdd(&cur[d], 1);
    nbr[pos] = es[i];
  }
}

// ---------------------------- fused node kernel ----------------------------
// 64 nodes / 256-thread block.
// mm phase: thread t: c = t&7 (16-col group j0=c*16), nA = t>>3 (0..31)
//   -> handles nodes nA and nA+32. wb: swizzled weight chunk, per-c stride 516
//   dwords (bank quad 4c -> conflict-free ds_read_b128 with 8-way broadcast).
// gather phase (NEW): 4 threads per node (node = t>>2, q = t&3), each owns a
//   contiguous 32-float chunk. All 64 nodes gather CONCURRENTLY; per edge a
//   thread issues 8 independent float4 loads (8-deep MLP). This replaces the
//   old per-wave 16-node serial loop (~16x shorter latency chain).
// ---------------------------------------------------------------------------
__device__ __forceinline__ void mm_accum(const float* __restrict__ W,
                                         float (*xs)[130], float* wb,
                                         float2* acc0, float2* acc1,
                                         int tid, int nA, int c)
{
  for (int mc = 0; mc < 4; mc++) {
    __syncthreads();                       // wb safe to overwrite
    {
      int m = tid >> 3;                    // 0..31
      const float4* s4 = (const float4*)(W + (size_t)(mc * 32 + m) * H + c * 16);
      float4* dd = (float4*)(wb + c * 516 + m * 16);
      dd[0] = s4[0]; dd[1] = s4[1]; dd[2] = s4[2]; dd[3] = s4[3];
    }
    __syncthreads();
    const float* xr0 = &xs[nA][mc * 32];
    const float* xr1 = &xs[nA + 32][mc * 32];
    const float4* wq = (const float4*)(wb + c * 516);
#pragma unroll 4
    for (int m = 0; m < 32; m++) {
      float xm0 = xr0[m], xm1 = xr1[m];
      const float4* w4 = wq + m * 4;
#pragma unroll
      for (int q = 0; q < 4; q++) {
        float4 w = w4[q];
        acc0[2*q].x   += xm0 * w.x; acc0[2*q].y   += xm0 * w.y;
        acc0[2*q+1].x += xm0 * w.z; acc0[2*q+1].y += xm0 * w.w;
        acc1[2*q].x   += xm1 * w.x; acc1[2*q].y   += xm1 * w.y;
        acc1[2*q+1].x += xm1 * w.z; acc1[2*q+1].y += xm1 * w.w;
      }
    }
  }
}

__global__ __launch_bounds__(256, 3) void k_fused(
    const float* __restrict__ xu, const float* __restrict__ xt,
    const float* __restrict__ xd,
    const int* __restrict__ off0, const int* __restrict__ nbr0,
    const int* __restrict__ off1, const int* __restrict__ nbr1,
    const int* __restrict__ off2, const int* __restrict__ nbr2,
    const float* __restrict__ Am, const float* __restrict__ W2T,
    const float* __restrict__ cvec, const float* __restrict__ b2f,
    float* __restrict__ out, int NU)
{
  __shared__ float xs[64][130];
  __shared__ float wb[8 * 516];
  int tid = threadIdx.x;
  int c = tid & 7, j0 = c * 16, nA = tid >> 3;
  int node = tid >> 2, q = tid & 3;        // gather mapping
  int g0 = blockIdx.x * 64;
  int g = g0 + node;

  float2 acc0[8], acc1[8];
#pragma unroll
  for (int qq = 0; qq < 8; qq++) {
    acc0[qq] = make_float2(cvec[j0 + 2*qq], cvec[j0 + 2*qq + 1]);
    acc1[qq] = acc0[qq];
  }

  for (int s = 0; s < 4; s++) {
    __syncthreads();                       // xs safe to overwrite
    float4 A[8];
#pragma unroll
    for (int i = 0; i < 8; i++) A[i] = make_float4(0.f, 0.f, 0.f, 0.f);

    if (g < NU) {
      if (s == 3) {
        const float4* src = (const float4*)(xu + (size_t)g * H) + q * 8;
#pragma unroll
        for (int i = 0; i < 8; i++) A[i] = src[i];
      } else {
        const float* xsrc = (s == 0) ? xt : (s == 1) ? xd : xu;
        const int* offp = (s == 0) ? off0 : (s == 1) ? off1 : off2;
        const int* nbrp = (s == 0) ? nbr0 : (s == 1) ? nbr1 : nbr2;
        int beg = offp[g], end = offp[g + 1];
        for (int e = beg; e < end; e++) {
          int srow = nbrp[e];
          const float4* src = (const float4*)(xsrc + (size_t)srow * H) + q * 8;
          float4 v[8];
#pragma unroll
          for (int i = 0; i < 8; i++) v[i] = src[i];
#pragma unroll
          for (int i = 0; i < 8; i++) {
            A[i].x += v[i].x; A[i].y += v[i].y;
            A[i].z += v[i].z; A[i].w += v[i].w;
          }
        }
        int d = end - beg;
        float inv = 1.f / (float)(d > 0 ? d : 1);
#pragma unroll
        for (int i = 0; i < 8; i++) {
          A[i].x *= inv; A[i].y *= inv; A[i].z *= inv; A[i].w *= inv;
        }
      }
    }
    // write chunk to xs (float2: rows are 8B-aligned with 130-dword stride)
    float* xrow = &xs[node][q * 32];
#pragma unroll
    for (int i = 0; i < 8; i++) {
      ((float2*)xrow)[2*i]     = make_float2(A[i].x, A[i].y);
      ((float2*)xrow)[2*i + 1] = make_float2(A[i].z, A[i].w);
    }
    __syncthreads();
    mm_accum(Am + (size_t)s * H * H, xs, wb, acc0, acc1, tid, nA, c);
  }

  __syncthreads();
  // h = relu(pre) -> xs
#pragma unroll
  for (int qq = 0; qq < 8; qq++) {
    float2 a = acc0[qq], b = acc1[qq];
    xs[nA][j0 + 2*qq]       = a.x > 0.f ? a.x : 0.f;
    xs[nA][j0 + 2*qq + 1]   = a.y > 0.f ? a.y : 0.f;
    xs[nA+32][j0 + 2*qq]     = b.x > 0.f ? b.x : 0.f;
    xs[nA+32][j0 + 2*qq + 1] = b.y > 0.f ? b.y : 0.f;
  }
  __syncthreads();
#pragma unroll
  for (int qq = 0; qq < 8; qq++) {
    acc0[qq] = make_float2(b2f[j0 + 2*qq], b2f[j0 + 2*qq + 1]);
    acc1[qq] = acc0[qq];
  }
  mm_accum(W2T, xs, wb, acc0, acc1, tid, nA, c);

  int gA = g0 + nA, gB = gA + 32;
  if (gA < NU) {
    float4* po = (float4*)(out + (size_t)gA * H + j0);
#pragma unroll
    for (int qq = 0; qq < 4; qq++)
      po[qq] = make_float4(acc0[2*qq].x, acc0[2*qq].y, acc0[2*qq+1].x, acc0[2*qq+1].y);
  }
  if (gB < NU) {
    float4* po = (float4*)(out + (size_t)gB * H + j0);
#pragma unroll
    for (int qq = 0; qq < 4; qq++)
      po[qq] = make_float4(acc1[2*qq].x, acc1[2*qq].y, acc1[2*qq+1].x, acc1[2*qq+1].y);
  }
}

extern "C" void kernel_launch(void* const* d_in, const int* in_sizes, int n_in,
                              void* d_out, int out_size, void* d_ws, size_t ws_size,
                              hipStream_t stream) {
  (void)n_in; (void)out_size; (void)ws_size;
  const float* xu = (const float*)d_in[0];
  const float* xt = (const float*)d_in[1];
  const float* xd = (const float*)d_in[2];
  const int* ess[3] = { (const int*)d_in[3], (const int*)d_in[5], (const int*)d_in[7] };
  const int* eds[3] = { (const int*)d_in[4], (const int*)d_in[6], (const int*)d_in[8] };
  const float* Wl = (const float*)d_in[9];
  const float* bl = (const float*)d_in[10];
  const float* Wr = (const float*)d_in[11];
  const float* W1 = (const float*)d_in[12];
  const float* b1 = (const float*)d_in[13];
  const float* W2 = (const float*)d_in[14];
  const float* b2 = (const float*)d_in[15];
  int Es[3] = { in_sizes[3], in_sizes[5], in_sizes[7] };
  int Emax = Es[0] > Es[1] ? Es[0] : Es[1];
  if (Es[2] > Emax) Emax = Es[2];

  const int NU = in_sizes[0] / H;          // 200000
  const int NB = (NU + 255) / 256;         // scan blocks
  float* out = (float*)d_out;

  // ---- workspace layout ----
  char* p = (char*)d_ws;
  size_t pos = 0;
  auto take = [&](size_t bytes) -> char* {
    char* r = p + pos;
    pos = (pos + bytes + 255) & ~(size_t)255;
    return r;
  };
  float* Am   = (float*)take((size_t)4 * H * H * sizeof(float));
  float* W2T  = (float*)take((size_t)H * H * sizeof(float));
  float* cvec = (float*)take(512);
  float* b2f  = (float*)take(512);
  int* curA   = (int*)take((size_t)3 * NU * sizeof(int));           // deg/cursor
  int* offA   = (int*)take((size_t)3 * (NU + 1) * sizeof(int));     // CSR offsets
  int* bsumA  = (int*)take((size_t)3 * (NB + 1) * sizeof(int));
  int* nbr[3];
  for (int r = 0; r < 3; r++) nbr[r] = (int*)take((size_t)Es[r] * sizeof(int));

  precompute_kernel<<<641, 128, 0, stream>>>(Wl, bl, Wr, W1, b1, W2, b2,
                                             Am, W2T, cvec, b2f);
  hipMemsetAsync(curA, 0, (size_t)3 * NU * sizeof(int), stream);

  dim3 ge((Emax + 255) / 256, 3);
  dim3 gn(NB, 3);
  k_hist3<<<ge, 256, 0, stream>>>(eds[0], eds[1], eds[2], curA,
                                  NU, Es[0], Es[1], Es[2]);
  k_scan1<<<gn, 256, 0, stream>>>(curA, offA, bsumA, NU, NB + 1);
  k_scan2<<<dim3(1, 3), 1024, 0, stream>>>(bsumA, NB, NB + 1);
  k_scan3c<<<gn, 256, 0, stream>>>(offA, bsumA, curA, NU, NB + 1);
  k_scatter3<<<ge, 256, 0, stream>>>(ess[0], ess[1], ess[2],
                                     eds[0], eds[1], eds[2],
                                     curA, nbr[0], nbr[1], nbr[2],
                                     NU, Es[0], Es[1], Es[2]);

  k_fused<<<(NU + 63) / 64, 256, 0, stream>>>(
      xu, xt, xd,
      offA, nbr[0], offA + (NU + 1), nbr[1], offA + 2 * (NU + 1), nbr[2],
      Am, W2T, cvec, b2f, out, NU);
}